// Round 4
// baseline (345.070 us; speedup 1.0000x reference)
//
#include <hip/hip_runtime.h>

typedef unsigned short u16;
typedef unsigned int u32;
typedef short bf16x8 __attribute__((ext_vector_type(8)));
typedef float f32x4 __attribute__((ext_vector_type(4)));

#define CIN 256
#define COUT 256

__device__ __forceinline__ u16 f2b(float f) {   // f32 -> bf16, round-nearest-even
  u32 u = __float_as_uint(f);
  u += 0x7fffu + ((u >> 16) & 1u);
  return (u16)(u >> 16);
}
__device__ __forceinline__ u32 packbf(float lo, float hi) {
  return (u32)f2b(lo) | ((u32)f2b(hi) << 16);
}

// -------------------- K0: weight permute + f32->bf16 --------------------
// W2[o][kk*256+c]  = bf16(w_def[o][c][kk])   (256 x 2304)
// Wm2[cm][kk*256+c] = bf16(w_mod[cm][c][kk]) (32 x 2304, rows 27..31 zero)
__global__ void k_permw(const float* __restrict__ w_mod, const float* __restrict__ w_def,
                        u16* __restrict__ Wm2, u16* __restrict__ W2) {
  int idx = blockIdx.x * 256 + threadIdx.x;
  if (idx < COUT * 2304) {
    int o = idx / 2304, r = idx - o * 2304;
    int kk = r >> 8, c = r & 255;
    W2[idx] = f2b(w_def[(o * 256 + c) * 9 + kk]);
  }
  int idx2 = idx - COUT * 2304;
  if (idx2 >= 0 && idx2 < 32 * 2304) {
    int cm = idx2 / 2304, r = idx2 - cm * 2304;
    int kk = r >> 8, c = r & 255;
    Wm2[idx2] = (cm < 27) ? f2b(w_mod[(cm * 256 + c) * 9 + kk]) : (u16)0;
  }
}

// -------------------- K1: mod conv (MFMA) + bilinear coef epilogue ----------
// grid 256: blk = b*64 + y (one image row). 256 threads (4 waves).
__global__ __launch_bounds__(256) void k_modconv(
    const float* __restrict__ x, const u16* __restrict__ Wm2,
    int2* __restrict__ cidx, float4* __restrict__ cwt) {
  __shared__ __align__(16) u16 As[64][72];   // [m=px][c]
  __shared__ __align__(16) u16 Bs[32][72];   // [cm][c]
  __shared__ float mods[32][66];             // [cm][px]
  int t = threadIdx.x;
  int l = t & 63;
  int w = __builtin_amdgcn_readfirstlane(t >> 6);
  int blk = blockIdx.x;
  int b = blk >> 6, y = blk & 63;
  const float* xb = x + b * (CIN * 4096);
  f32x4 zero = {0.f, 0.f, 0.f, 0.f};
  f32x4 acc0 = zero, acc1 = zero;
  int ml = l & 15, kq = l >> 4;

  for (int chunk = 0; chunk < 36; ++chunk) {
    int kk = chunk >> 2, c0 = (chunk & 3) << 6;
    int ky = kk / 3, kx = kk - 3 * ky;
    int ysrc = y + ky - 1;
    __syncthreads();
    { // A-tile: row m=l holds bf16(x[b][c][y+ky-1][l+kx-1]) (zero-padded)
      int xsrc = l + kx - 1;
      int xc = min(max(xsrc, 0), 63);
      bool xv = (xsrc >= 0) && (xsrc < 64);
      u32 pk[8];
      if (ysrc >= 0 && ysrc < 64) {
        const float* p0 = xb + (c0 + w * 16) * 4096 + ysrc * 64 + xc;
#pragma unroll
        for (int j = 0; j < 8; ++j) {
          float vlo = p0[(2 * j) * 4096];
          float vhi = p0[(2 * j + 1) * 4096];
          pk[j] = xv ? packbf(vlo, vhi) : 0u;
        }
      } else {
#pragma unroll
        for (int j = 0; j < 8; ++j) pk[j] = 0u;
      }
      uint4* dst = (uint4*)&As[l][w * 16];
      dst[0] = make_uint4(pk[0], pk[1], pk[2], pk[3]);
      dst[1] = make_uint4(pk[4], pk[5], pk[6], pk[7]);
    }
    { // B-tile 32x64
      int n = t >> 3, cb = t & 7;
      *(uint4*)&Bs[n][cb << 3] =
          *(const uint4*)(Wm2 + n * 2304 + (kk << 8) + c0 + (cb << 3));
    }
    __syncthreads();
#pragma unroll
    for (int ks = 0; ks < 2; ++ks) {
      bf16x8 a  = *(const bf16x8*)&As[w * 16 + ml][ks * 32 + kq * 8];
      bf16x8 b0 = *(const bf16x8*)&Bs[ml][ks * 32 + kq * 8];
      bf16x8 b1 = *(const bf16x8*)&Bs[16 + ml][ks * 32 + kq * 8];
      acc0 = __builtin_amdgcn_mfma_f32_16x16x32_bf16(a, b0, acc0, 0, 0, 0);
      acc1 = __builtin_amdgcn_mfma_f32_16x16x32_bf16(a, b1, acc1, 0, 0, 0);
    }
  }
  // C/D: col=lane&15 (cm), row=kq*4+r (m within wave's 16)
#pragma unroll
  for (int r = 0; r < 4; ++r) {
    mods[ml][w * 16 + kq * 4 + r]      = acc0[r];
    mods[16 + ml][w * 16 + kq * 4 + r] = acc1[r];
  }
  __syncthreads();
  // coef epilogue: 9 taps x 64 px
  for (int i2 = t; i2 < 576; i2 += 256) {
    int kk = i2 >> 6, px = i2 & 63;
    float dy = mods[2 * kk][px];
    float dx = mods[2 * kk + 1][px];
    float msk = 1.f / (1.f + __expf(-mods[18 + kk][px]));
    int ky = kk / 3, kx = kk - 3 * ky;
    float py  = dy + (float)(y + ky - 1);
    float pxx = dx + (float)(px + kx - 1);
    float y0f = floorf(py), x0f = floorf(pxx);
    float fy = py - y0f, fx = pxx - x0f;
    int y0 = (int)y0f, x0 = (int)x0f;
    float vy0 = (y0 >= 0 && y0 < 64) ? msk : 0.f;
    float vy1 = (y0 + 1 >= 0 && y0 + 1 < 64) ? msk : 0.f;
    float w00 = (1.f - fy) * (1.f - fx) * vy0;
    float w01 = (1.f - fy) * fx * vy0;
    float w10 = fy * (1.f - fx) * vy1;
    float w11 = fy * fx * vy1;
    // 2-element window [xb2, xb2+1]; x-validity folded into weights
    int xb2 = min(max(x0, 0), 62);
    float wA0 = (xb2 == x0) ? w00 : ((xb2 == x0 + 1) ? w01 : 0.f);
    float wB0 = (xb2 + 1 == x0) ? w00 : ((xb2 + 1 == x0 + 1) ? w01 : 0.f);
    float wA1 = (xb2 == x0) ? w10 : ((xb2 == x0 + 1) ? w11 : 0.f);
    float wB1 = (xb2 + 1 == x0) ? w10 : ((xb2 + 1 == x0 + 1) ? w11 : 0.f);
    int ib0 = min(max(y0, 0), 63) * 64 + xb2;        // <= 4094
    int ib1 = min(max(y0 + 1, 0), 63) * 64 + xb2;    // <= 4094
    int ci = ((b * 9 + kk) << 12) + (y << 6) + px;
    cidx[ci] = make_int2(ib0, ib1);
    cwt[ci]  = make_float4(wA0, wB0, wA1, wB1);
  }
}

// -------------------- K2: fused gather + GEMM + epilogue --------------------
// grid 256: blk = b*64 + y. BM=64 (one row), BN=256, BK=64. wave w owns n in [w*64, w*64+64).
__global__ __launch_bounds__(256) void k_main(
    const float* __restrict__ x, const u16* __restrict__ W2,
    const float* __restrict__ b_def,
    const int2* __restrict__ cidx, const float4* __restrict__ cwt,
    float* __restrict__ out) {
  __shared__ __align__(16) u16 As[64][72];    // sampled tile [m][c]
  __shared__ __align__(16) u16 Bs[256][72];   // weights [n][c]
  int t = threadIdx.x;
  int l = t & 63;
  int w = __builtin_amdgcn_readfirstlane(t >> 6);
  int blk = blockIdx.x;
  int b = blk >> 6, y = blk & 63;
  const float* xb = x + b * (CIN * 4096);
  f32x4 zero = {0.f, 0.f, 0.f, 0.f};
  f32x4 acc[4][4];
#pragma unroll
  for (int i = 0; i < 4; ++i)
#pragma unroll
    for (int j = 0; j < 4; ++j) acc[i][j] = zero;
  int ml = l & 15, kq = l >> 4;

  for (int chunk = 0; chunk < 36; ++chunk) {
    int kk = chunk >> 2, c0 = (chunk & 3) << 6;
    __syncthreads();
    { // build sampled A-tile: thread: m=l, c-strip [c0+w*16, +16)
      int ci = ((b * 9 + kk) << 12) + (y << 6) + l;
      int2 ib = cidx[ci];
      float4 wt = cwt[ci];
      const float* pl = xb + (c0 + w * 16) * 4096;
      u32 pk[8];
#pragma unroll
      for (int j = 0; j < 8; ++j) {
        float s01[2];
#pragma unroll
        for (int jj = 0; jj < 2; ++jj) {
          const float* p = pl + (2 * j + jj) * 4096;
          float f00 = p[ib.x];
          float f01 = p[ib.x + 1];
          float f10 = p[ib.y];
          float f11 = p[ib.y + 1];
          float s = f00 * wt.x;
          s = fmaf(f01, wt.y, s);
          s = fmaf(f10, wt.z, s);
          s = fmaf(f11, wt.w, s);
          s01[jj] = s;
        }
        pk[j] = packbf(s01[0], s01[1]);
      }
      uint4* dst = (uint4*)&As[l][w * 16];
      dst[0] = make_uint4(pk[0], pk[1], pk[2], pk[3]);
      dst[1] = make_uint4(pk[4], pk[5], pk[6], pk[7]);
    }
    { // B-tile 256x64
      int cb = t & 7, nb = t >> 3;
#pragma unroll
      for (int rr = 0; rr < 8; ++rr) {
        int n = rr * 32 + nb;
        *(uint4*)&Bs[n][cb << 3] =
            *(const uint4*)(W2 + n * 2304 + (kk << 8) + c0 + (cb << 3));
      }
    }
    __syncthreads();
#pragma unroll
    for (int ks = 0; ks < 2; ++ks) {
      bf16x8 a[4], bfr[4];
#pragma unroll
      for (int mt = 0; mt < 4; ++mt)
        a[mt] = *(const bf16x8*)&As[mt * 16 + ml][ks * 32 + kq * 8];
#pragma unroll
      for (int nt = 0; nt < 4; ++nt)
        bfr[nt] = *(const bf16x8*)&Bs[w * 64 + nt * 16 + ml][ks * 32 + kq * 8];
#pragma unroll
      for (int mt = 0; mt < 4; ++mt)
#pragma unroll
        for (int nt = 0; nt < 4; ++nt)
          acc[mt][nt] = __builtin_amdgcn_mfma_f32_16x16x32_bf16(a[mt], bfr[nt], acc[mt][nt], 0, 0, 0);
    }
  }
  // epilogue: bias + direct f32 stores.
  // C/D layout: n (col) = ml within each 16-block; m (row) = kq*4 + r.
#pragma unroll
  for (int nt = 0; nt < 4; ++nt) {
    int n = w * 64 + nt * 16 + ml;
    float bias = b_def[n];
    float* op = out + ((b * 256 + n) * 64 + y) * 64;
#pragma unroll
    for (int mt = 0; mt < 4; ++mt) {
      float4 v;
      v.x = acc[mt][nt][0] + bias;
      v.y = acc[mt][nt][1] + bias;
      v.z = acc[mt][nt][2] + bias;
      v.w = acc[mt][nt][3] + bias;
      *(float4*)(op + mt * 16 + kq * 4) = v;
    }
  }
}

// -------------------- launcher --------------------
extern "C" void kernel_launch(void* const* d_in, const int* in_sizes, int n_in,
                              void* d_out, int out_size, void* d_ws, size_t ws_size,
                              hipStream_t stream) {
  const float* x     = (const float*)d_in[0];
  const float* w_mod = (const float*)d_in[1];
  const float* w_def = (const float*)d_in[2];
  const float* b_def = (const float*)d_in[3];
  float* out = (float*)d_out;
  char* ws = (char*)d_ws;
  // ws layout (16B-aligned): W2 1,179,648 | Wm2 147,456 | cidx 1,179,648 | cwt 2,359,296  (total ~4.87 MB)
  u16*    W2   = (u16*)(ws);
  u16*    Wm2  = (u16*)(ws + 1179648);
  int2*   cidx = (int2*)(ws + 1179648 + 147456);
  float4* cwt  = (float4*)(ws + 1179648 + 147456 + 1179648);

  hipLaunchKernelGGL(k_permw, dim3(2592), dim3(256), 0, stream, w_mod, w_def, Wm2, W2);
  hipLaunchKernelGGL(k_modconv, dim3(256), dim3(256), 0, stream, x, Wm2, cidx, cwt);
  hipLaunchKernelGGL(k_main, dim3(256), dim3(256), 0, stream, x, W2, b_def, cidx, cwt, out);
}

// Round 5
// 164.085 us; speedup vs baseline: 2.1030x; 2.1030x over previous
//
#include <hip/hip_runtime.h>

typedef unsigned short u16;
typedef unsigned int u32;
typedef short bf16x8 __attribute__((ext_vector_type(8)));
typedef float f32x4 __attribute__((ext_vector_type(4)));

#define CIN 256
#define COUT 256

__device__ __forceinline__ u16 f2b(float f) {   // f32 -> bf16 RNE
  u32 u = __float_as_uint(f);
  u += 0x7fffu + ((u >> 16) & 1u);
  return (u16)(u >> 16);
}
__device__ __forceinline__ u32 packbf(float lo, float hi) {
  return (u32)f2b(lo) | ((u32)f2b(hi) << 16);
}
// bilinear combine of one bf16x2 dword per corner -> packed bf16x2 result
__device__ __forceinline__ u32 bil2(u32 u00, u32 u01, u32 u10, u32 u11, float4 wt) {
  float s0 = __uint_as_float(u00 << 16) * wt.x;
  s0 = fmaf(__uint_as_float(u01 << 16), wt.y, s0);
  s0 = fmaf(__uint_as_float(u10 << 16), wt.z, s0);
  s0 = fmaf(__uint_as_float(u11 << 16), wt.w, s0);
  float s1 = __uint_as_float(u00 & 0xffff0000u) * wt.x;
  s1 = fmaf(__uint_as_float(u01 & 0xffff0000u), wt.y, s1);
  s1 = fmaf(__uint_as_float(u10 & 0xffff0000u), wt.z, s1);
  s1 = fmaf(__uint_as_float(u11 & 0xffff0000u), wt.w, s1);
  return packbf(s0, s1);
}

// -------- K0a: weight permute + f32->bf16 (LDS transpose, coalesced) --------
// W2[o][kk*256+c] = bf16(w_def[o][c][kk]); Wm2[cm][...] likewise (rows 27..31 zero)
__global__ __launch_bounds__(256) void k_permw(
    const float* __restrict__ w_mod, const float* __restrict__ w_def,
    u16* __restrict__ Wm2, u16* __restrict__ W2) {
  __shared__ float L[2304];
  int t = threadIdx.x, g = blockIdx.x;
  if (g < 256) {
    const float* src = w_def + g * 2304;
    for (int j = t; j < 2304; j += 256) L[j] = src[j];
    __syncthreads();
    u16* dst = W2 + g * 2304;
    for (int j = t; j < 2304; j += 256) {
      int kk = j >> 8, c = j & 255;
      dst[j] = f2b(L[c * 9 + kk]);
    }
  } else {
    int cm = g - 256;
    if (cm < 27) {
      const float* src = w_mod + cm * 2304;
      for (int j = t; j < 2304; j += 256) L[j] = src[j];
    }
    __syncthreads();
    u16* dst = Wm2 + cm * 2304;
    for (int j = t; j < 2304; j += 256) {
      int kk = j >> 8, c = j & 255;
      dst[j] = (cm < 27) ? f2b(L[c * 9 + kk]) : (u16)0;
    }
  }
}

// -------- K0b: x NCHW f32 -> xT[b][pos][c] bf16 (channels-last) --------
// grid 1024: g = b*256 + ct*64 + pt  (64c x 64pos tile)
__global__ __launch_bounds__(256) void k_xT(const float* __restrict__ x,
                                            u16* __restrict__ xT) {
  __shared__ __align__(16) u16 T[64][72];
  int t = threadIdx.x, g = blockIdx.x;
  int b = g >> 8, ct = (g >> 6) & 3, pt = g & 63;
  int c0 = ct << 6, pos0 = pt << 6;
  {
    int cl = t >> 2, pb = (t & 3) << 4;
    const float* p = x + (((b << 8) + c0 + cl) << 12) + pos0 + pb;
#pragma unroll
    for (int i = 0; i < 4; ++i) {
      float4 v = *(const float4*)(p + i * 4);
      int pp = pb + i * 4;
      T[pp][cl] = f2b(v.x); T[pp + 1][cl] = f2b(v.y);
      T[pp + 2][cl] = f2b(v.z); T[pp + 3][cl] = f2b(v.w);
    }
  }
  __syncthreads();
  {
    int pl = t >> 2, q = t & 3;
    u16* dst = xT + (((b << 12) + pos0 + pl) << 8) + c0 + (q << 4);
    *(uint4*)dst = *(const uint4*)&T[pl][q << 4];
    *(uint4*)(dst + 8) = *(const uint4*)&T[pl][(q << 4) + 8];
  }
}

// -------- K1: mod conv (MFMA) + bilinear coef epilogue --------
// grid 256, XCD swizzle: b=(g&7)>>1, y=(g>>3)*2+(g&1). 256 threads.
__global__ __launch_bounds__(256) void k_modconv(
    const u16* __restrict__ xT, const u16* __restrict__ Wm2,
    int2* __restrict__ cidx, float4* __restrict__ cwt) {
  __shared__ __align__(16) u16 As[64][72];
  __shared__ __align__(16) u16 Bs[32][72];
  __shared__ float mods[32][66];
  int t = threadIdx.x;
  int l = t & 63;
  int w = t >> 6;
  int g = blockIdx.x;
  int b = (g & 7) >> 1, y = ((g >> 3) << 1) + (g & 1);
  const u16* xTb = xT + (b << 20);   // b * 4096*256
  f32x4 zero = {0.f, 0.f, 0.f, 0.f};
  f32x4 acc0 = zero, acc1 = zero;
  int ml = l & 15, kq = l >> 4;

  for (int chunk = 0; chunk < 36; ++chunk) {
    int kk = chunk >> 2, c0 = (chunk & 3) << 6;
    int ky = kk / 3, kx = kk - 3 * ky;
    int ysrc = y + ky - 1;
    __syncthreads();
    { // A-tile from xT (coalesced bf16)
      int px = t >> 2, q = t & 3;
      int xsrc = px + kx - 1;
      uint4 v0 = make_uint4(0, 0, 0, 0), v1 = v0;
      if (xsrc >= 0 && xsrc < 64 && ysrc >= 0 && ysrc < 64) {
        const u16* p = xTb + (((ysrc << 6) + xsrc) << 8) + c0 + (q << 4);
        v0 = *(const uint4*)p;
        v1 = *(const uint4*)(p + 8);
      }
      *(uint4*)&As[px][q << 4] = v0;
      *(uint4*)&As[px][(q << 4) + 8] = v1;
    }
    { // B-tile 32x64
      int n = t >> 3, cb = t & 7;
      *(uint4*)&Bs[n][cb << 3] =
          *(const uint4*)(Wm2 + n * 2304 + (kk << 8) + c0 + (cb << 3));
    }
    __syncthreads();
#pragma unroll
    for (int ks = 0; ks < 2; ++ks) {
      bf16x8 a  = *(const bf16x8*)&As[w * 16 + ml][ks * 32 + (kq << 3)];
      bf16x8 b0 = *(const bf16x8*)&Bs[ml][ks * 32 + (kq << 3)];
      bf16x8 b1 = *(const bf16x8*)&Bs[16 + ml][ks * 32 + (kq << 3)];
      acc0 = __builtin_amdgcn_mfma_f32_16x16x32_bf16(a, b0, acc0, 0, 0, 0);
      acc1 = __builtin_amdgcn_mfma_f32_16x16x32_bf16(a, b1, acc1, 0, 0, 0);
    }
  }
#pragma unroll
  for (int r = 0; r < 4; ++r) {
    mods[ml][w * 16 + kq * 4 + r]      = acc0[r];
    mods[16 + ml][w * 16 + kq * 4 + r] = acc1[r];
  }
  __syncthreads();
  for (int i2 = t; i2 < 576; i2 += 256) {
    int kk = i2 >> 6, px = i2 & 63;
    float dy = mods[2 * kk][px];
    float dx = mods[2 * kk + 1][px];
    float msk = 1.f / (1.f + __expf(-mods[18 + kk][px]));
    int ky = kk / 3, kx = kk - 3 * ky;
    float py  = dy + (float)(y + ky - 1);
    float pxx = dx + (float)(px + kx - 1);
    float y0f = floorf(py), x0f = floorf(pxx);
    float fy = py - y0f, fx = pxx - x0f;
    int y0 = (int)y0f, x0 = (int)x0f;
    float vy0 = (y0 >= 0 && y0 < 64) ? msk : 0.f;
    float vy1 = (y0 + 1 >= 0 && y0 + 1 < 64) ? msk : 0.f;
    float w00 = (1.f - fy) * (1.f - fx) * vy0;
    float w01 = (1.f - fy) * fx * vy0;
    float w10 = fy * (1.f - fx) * vy1;
    float w11 = fy * fx * vy1;
    int xb2 = min(max(x0, 0), 62);
    float wA0 = (xb2 == x0) ? w00 : ((xb2 == x0 + 1) ? w01 : 0.f);
    float wB0 = (xb2 + 1 == x0) ? w00 : ((xb2 + 1 == x0 + 1) ? w01 : 0.f);
    float wA1 = (xb2 == x0) ? w10 : ((xb2 == x0 + 1) ? w11 : 0.f);
    float wB1 = (xb2 + 1 == x0) ? w10 : ((xb2 + 1 == x0 + 1) ? w11 : 0.f);
    int ib0 = min(max(y0, 0), 63) * 64 + xb2;
    int ib1 = min(max(y0 + 1, 0), 63) * 64 + xb2;
    int ci = ((b * 9 + kk) << 12) + (y << 6) + px;
    cidx[ci] = make_int2(ib0, ib1);
    cwt[ci]  = make_float4(wA0, wB0, wA1, wB1);
  }
}

// -------- K2: fused gather + GEMM, pipelined (As dbuf, B in regs) --------
// grid 256 (swizzled), 512 threads (8 waves). Wave w owns n in [w*32, w*32+32).
__global__ __launch_bounds__(512, 2) void k_main(
    const u16* __restrict__ xT, const u16* __restrict__ W2,
    const float* __restrict__ b_def,
    const int2* __restrict__ cidx, const float4* __restrict__ cwt,
    float* __restrict__ out) {
  __shared__ __align__(16) u16 As[2][64][72];
  __shared__ __align__(16) int2 Cs_i[576];
  __shared__ __align__(16) float4 Cs_w[576];
  int t = threadIdx.x;
  int l = t & 63;
  int w = t >> 6;
  int g = blockIdx.x;
  int b = (g & 7) >> 1, y = ((g >> 3) << 1) + (g & 1);
  const u16* xTb = xT + (b << 20);
  int gm = t >> 3, go = t & 7;          // gather: pixel, channel-octet
  int ml = l & 15, kq = l >> 4;         // mfma lane mapping
  int nrow0 = w * 32 + ml, nrow1 = nrow0 + 16;

  f32x4 zero = {0.f, 0.f, 0.f, 0.f};
  f32x4 acc[4][2];
#pragma unroll
  for (int i = 0; i < 4; ++i) { acc[i][0] = zero; acc[i][1] = zero; }

  // stage all 9 taps' coefs for this (b,y) row into LDS
  for (int i = t; i < 576; i += 512) {
    int kk = i >> 6, px = i & 63;
    int ci = ((b * 9 + kk) << 12) + (y << 6) + px;
    Cs_i[i] = cidx[ci];
    Cs_w[i] = cwt[ci];
  }
  __syncthreads();

  uint4 rA0, rA1, rA2, rA3;            // 4 corners x 8ch
  float4 rwt;
  uint4 RA0, RA1, RA2, RA3;            // B-frag buffer A (nt0ks0,nt1ks0,nt0ks1,nt1ks1)
  uint4 RB0, RB1, RB2, RB3;            // B-frag buffer B

#define ISSUE(chunk, R0, R1, R2, R3)                                         \
  { int kk_ = (chunk) >> 2, c0_ = ((chunk) & 3) << 6;                        \
    int cI_ = (kk_ << 6) + gm;                                               \
    int2 ib_ = Cs_i[cI_];                                                    \
    rwt = Cs_w[cI_];                                                         \
    const u16* p0_ = xTb + (ib_.x << 8) + c0_ + (go << 3);                   \
    const u16* p1_ = xTb + (ib_.y << 8) + c0_ + (go << 3);                   \
    rA0 = *(const uint4*)p0_;  rA1 = *(const uint4*)(p0_ + 256);             \
    rA2 = *(const uint4*)p1_;  rA3 = *(const uint4*)(p1_ + 256);             \
    const u16* pw_ = W2 + (kk_ << 8) + c0_ + (kq << 3);                      \
    R0 = *(const uint4*)(pw_ + nrow0 * 2304);                                \
    R1 = *(const uint4*)(pw_ + nrow1 * 2304);                                \
    R2 = *(const uint4*)(pw_ + nrow0 * 2304 + 32);                           \
    R3 = *(const uint4*)(pw_ + nrow1 * 2304 + 32); }

#define UNPACK(CUR)                                                          \
  { u32 q0_ = bil2(rA0.x, rA1.x, rA2.x, rA3.x, rwt);                         \
    u32 q1_ = bil2(rA0.y, rA1.y, rA2.y, rA3.y, rwt);                         \
    u32 q2_ = bil2(rA0.z, rA1.z, rA2.z, rA3.z, rwt);                         \
    u32 q3_ = bil2(rA0.w, rA1.w, rA2.w, rA3.w, rwt);                         \
    *(uint4*)&As[CUR][gm][go << 3] = make_uint4(q0_, q1_, q2_, q3_); }

#define DOMFMA(CUR, R0, R1, R2, R3)                                          \
  { bf16x8 a0_ = *(const bf16x8*)&As[CUR][ml][kq << 3];                      \
    bf16x8 a1_ = *(const bf16x8*)&As[CUR][16 + ml][kq << 3];                 \
    bf16x8 a2_ = *(const bf16x8*)&As[CUR][32 + ml][kq << 3];                 \
    bf16x8 a3_ = *(const bf16x8*)&As[CUR][48 + ml][kq << 3];                 \
    bf16x8 b0_ = *(const bf16x8*)&R0;                                        \
    bf16x8 b1_ = *(const bf16x8*)&R1;                                        \
    acc[0][0] = __builtin_amdgcn_mfma_f32_16x16x32_bf16(a0_, b0_, acc[0][0], 0,0,0); \
    acc[1][0] = __builtin_amdgcn_mfma_f32_16x16x32_bf16(a1_, b0_, acc[1][0], 0,0,0); \
    acc[2][0] = __builtin_amdgcn_mfma_f32_16x16x32_bf16(a2_, b0_, acc[2][0], 0,0,0); \
    acc[3][0] = __builtin_amdgcn_mfma_f32_16x16x32_bf16(a3_, b0_, acc[3][0], 0,0,0); \
    acc[0][1] = __builtin_amdgcn_mfma_f32_16x16x32_bf16(a0_, b1_, acc[0][1], 0,0,0); \
    acc[1][1] = __builtin_amdgcn_mfma_f32_16x16x32_bf16(a1_, b1_, acc[1][1], 0,0,0); \
    acc[2][1] = __builtin_amdgcn_mfma_f32_16x16x32_bf16(a2_, b1_, acc[2][1], 0,0,0); \
    acc[3][1] = __builtin_amdgcn_mfma_f32_16x16x32_bf16(a3_, b1_, acc[3][1], 0,0,0); \
    a0_ = *(const bf16x8*)&As[CUR][ml][32 + (kq << 3)];                      \
    a1_ = *(const bf16x8*)&As[CUR][16 + ml][32 + (kq << 3)];                 \
    a2_ = *(const bf16x8*)&As[CUR][32 + ml][32 + (kq << 3)];                 \
    a3_ = *(const bf16x8*)&As[CUR][48 + ml][32 + (kq << 3)];                 \
    b0_ = *(const bf16x8*)&R2;                                               \
    b1_ = *(const bf16x8*)&R3;                                               \
    acc[0][0] = __builtin_amdgcn_mfma_f32_16x16x32_bf16(a0_, b0_, acc[0][0], 0,0,0); \
    acc[1][0] = __builtin_amdgcn_mfma_f32_16x16x32_bf16(a1_, b0_, acc[1][0], 0,0,0); \
    acc[2][0] = __builtin_amdgcn_mfma_f32_16x16x32_bf16(a2_, b0_, acc[2][0], 0,0,0); \
    acc[3][0] = __builtin_amdgcn_mfma_f32_16x16x32_bf16(a3_, b0_, acc[3][0], 0,0,0); \
    acc[0][1] = __builtin_amdgcn_mfma_f32_16x16x32_bf16(a0_, b1_, acc[0][1], 0,0,0); \
    acc[1][1] = __builtin_amdgcn_mfma_f32_16x16x32_bf16(a1_, b1_, acc[1][1], 0,0,0); \
    acc[2][1] = __builtin_amdgcn_mfma_f32_16x16x32_bf16(a2_, b1_, acc[2][1], 0,0,0); \
    acc[3][1] = __builtin_amdgcn_mfma_f32_16x16x32_bf16(a3_, b1_, acc[3][1], 0,0,0); }

  ISSUE(0, RA0, RA1, RA2, RA3)
#pragma unroll 1
  for (int c2 = 0; c2 < 36; c2 += 2) {
    // even chunk -> As[0], B-frags in RA*; prefetch odd into RB*
    UNPACK(0)
    __syncthreads();
    ISSUE(c2 + 1, RB0, RB1, RB2, RB3)
    DOMFMA(0, RA0, RA1, RA2, RA3)
    // odd chunk -> As[1]; prefetch next even into RA*
    UNPACK(1)
    __syncthreads();
    if (c2 + 2 < 36) ISSUE(c2 + 2, RA0, RA1, RA2, RA3)
    DOMFMA(1, RB0, RB1, RB2, RB3)
  }

  // epilogue: bias + f32 stores (C/D: col=n=ml-block, row=kq*4+r)
#pragma unroll
  for (int nt = 0; nt < 2; ++nt) {
    int n = w * 32 + nt * 16 + ml;
    float bias = b_def[n];
    float* op = out + (((b << 8) + n) << 12) + (y << 6);
#pragma unroll
    for (int mt = 0; mt < 4; ++mt) {
      float4 v;
      v.x = acc[mt][nt][0] + bias;
      v.y = acc[mt][nt][1] + bias;
      v.z = acc[mt][nt][2] + bias;
      v.w = acc[mt][nt][3] + bias;
      *(float4*)(op + mt * 16 + kq * 4) = v;
    }
  }
#undef ISSUE
#undef UNPACK
#undef DOMFMA
}

// -------------------- launcher --------------------
extern "C" void kernel_launch(void* const* d_in, const int* in_sizes, int n_in,
                              void* d_out, int out_size, void* d_ws, size_t ws_size,
                              hipStream_t stream) {
  const float* x     = (const float*)d_in[0];
  const float* w_mod = (const float*)d_in[1];
  const float* w_def = (const float*)d_in[2];
  const float* b_def = (const float*)d_in[3];
  float* out = (float*)d_out;
  char* ws = (char*)d_ws;
  // ws: xT 8,388,608 | W2 1,179,648 | Wm2 147,456 | cidx 1,179,648 | cwt 2,359,296 = 13,254,656 B
  u16*    xT   = (u16*)(ws);
  u16*    W2   = (u16*)(ws + 8388608);
  u16*    Wm2  = (u16*)(ws + 8388608 + 1179648);
  int2*   cidx = (int2*)(ws + 8388608 + 1179648 + 147456);
  float4* cwt  = (float4*)(ws + 8388608 + 1179648 + 147456 + 1179648);

  hipLaunchKernelGGL(k_permw, dim3(288), dim3(256), 0, stream, w_mod, w_def, Wm2, W2);
  hipLaunchKernelGGL(k_xT, dim3(1024), dim3(256), 0, stream, x, xT);
  hipLaunchKernelGGL(k_modconv, dim3(256), dim3(256), 0, stream, xT, Wm2, cidx, cwt);
  hipLaunchKernelGGL(k_main, dim3(256), dim3(512), 0, stream, xT, W2, b_def, cidx, cwt, out);
}

// Round 6
// 158.168 us; speedup vs baseline: 2.1817x; 1.0374x over previous
//
#include <hip/hip_runtime.h>

typedef unsigned short u16;
typedef unsigned int u32;
typedef short bf16x8 __attribute__((ext_vector_type(8)));
typedef float f32x4 __attribute__((ext_vector_type(4)));

#define CIN 256
#define COUT 256

__device__ __forceinline__ u16 f2b(float f) {   // f32 -> bf16 RNE
  u32 u = __float_as_uint(f);
  u += 0x7fffu + ((u >> 16) & 1u);
  return (u16)(u >> 16);
}
__device__ __forceinline__ u32 packbf(float lo, float hi) {
  return (u32)f2b(lo) | ((u32)f2b(hi) << 16);
}
__device__ __forceinline__ u32 bil2(u32 u00, u32 u01, u32 u10, u32 u11, float4 wt) {
  float s0 = __uint_as_float(u00 << 16) * wt.x;
  s0 = fmaf(__uint_as_float(u01 << 16), wt.y, s0);
  s0 = fmaf(__uint_as_float(u10 << 16), wt.z, s0);
  s0 = fmaf(__uint_as_float(u11 << 16), wt.w, s0);
  float s1 = __uint_as_float(u00 & 0xffff0000u) * wt.x;
  s1 = fmaf(__uint_as_float(u01 & 0xffff0000u), wt.y, s1);
  s1 = fmaf(__uint_as_float(u10 & 0xffff0000u), wt.z, s1);
  s1 = fmaf(__uint_as_float(u11 & 0xffff0000u), wt.w, s1);
  return packbf(s0, s1);
}
// barrier that does NOT drain vmcnt: LDS-visibility only. Global loads
// issued before it remain in flight (consumer's own s_waitcnt vmcnt covers them).
__device__ __forceinline__ void bar() {
  asm volatile("s_waitcnt lgkmcnt(0)\n\ts_barrier" ::: "memory");
}

// -------- K0 (fused prep): g<1024: xT transpose tile; else weight permute ----
__global__ __launch_bounds__(256) void k_prep(
    const float* __restrict__ x, const float* __restrict__ w_mod,
    const float* __restrict__ w_def,
    u16* __restrict__ xT, u16* __restrict__ Wm2, u16* __restrict__ W2) {
  __shared__ __align__(16) char SB[9216];
  int t = threadIdx.x, g = blockIdx.x;
  if (g < 1024) {            // x NCHW f32 -> xT[b][pos][c] bf16
    u16 (*T)[72] = (u16(*)[72])SB;
    int b = g >> 8, ct = (g >> 6) & 3, pt = g & 63;
    int c0 = ct << 6, pos0 = pt << 6;
    {
      int cl = t >> 2, pb = (t & 3) << 4;
      const float* p = x + (((b << 8) + c0 + cl) << 12) + pos0 + pb;
#pragma unroll
      for (int i = 0; i < 4; ++i) {
        float4 v = *(const float4*)(p + i * 4);
        int pp = pb + i * 4;
        T[pp][cl] = f2b(v.x); T[pp + 1][cl] = f2b(v.y);
        T[pp + 2][cl] = f2b(v.z); T[pp + 3][cl] = f2b(v.w);
      }
    }
    __syncthreads();
    {
      int pl = t >> 2, q = t & 3;
      u16* dst = xT + (((b << 12) + pos0 + pl) << 8) + c0 + (q << 4);
      *(uint4*)dst = *(const uint4*)&T[pl][q << 4];
      *(uint4*)(dst + 8) = *(const uint4*)&T[pl][(q << 4) + 8];
    }
  } else {                   // weight permute + f32->bf16
    float* L = (float*)SB;
    int gg = g - 1024;
    if (gg < 256) {
      const float* src = w_def + gg * 2304;
      for (int j = t; j < 2304; j += 256) L[j] = src[j];
      __syncthreads();
      u16* dst = W2 + gg * 2304;
      for (int j = t; j < 2304; j += 256) {
        int kk = j >> 8, c = j & 255;
        dst[j] = f2b(L[c * 9 + kk]);
      }
    } else {
      int cm = gg - 256;
      if (cm < 27) {
        const float* src = w_mod + cm * 2304;
        for (int j = t; j < 2304; j += 256) L[j] = src[j];
      }
      __syncthreads();
      u16* dst = Wm2 + cm * 2304;
      for (int j = t; j < 2304; j += 256) {
        int kk = j >> 8, c = j & 255;
        dst[j] = (cm < 27) ? f2b(L[c * 9 + kk]) : (u16)0;
      }
    }
  }
}

// -------- K1: mod conv (MFMA, in-block split-K) + bilinear coef epilogue ----
// grid 256 swizzled, 512 threads. Group h = t>>8 does chunks [h*18, h*18+18).
// Within group: 4 waves split M (wl*16 px each), n 0..31 via acc0/acc1.
__global__ __launch_bounds__(512) void k_modconv(
    const u16* __restrict__ xT, const u16* __restrict__ Wm2,
    int2* __restrict__ cidx, float4* __restrict__ cwt) {
  __shared__ __align__(16) u16 As[2][2][64][72];  // [group][buf][px][c]
  __shared__ float mods2[2][32][66];              // partial [group][cm][px]
  int t = threadIdx.x;
  int l = t & 63;
  int w = t >> 6;
  int h = t >> 8;          // K-group
  int wl = w & 3;
  int tg = t & 255;
  int px = tg >> 2, q = tg & 3;
  int g = blockIdx.x;
  int b = (g & 7) >> 1, y = ((g >> 3) << 1) + (g & 1);
  const u16* xTb = xT + (b << 20);
  f32x4 zero = {0.f, 0.f, 0.f, 0.f};
  f32x4 acc0 = zero, acc1 = zero;
  int ml = l & 15, kq = l >> 4;

  uint4 VA0, VA1, VB0, VB1;
  uint4 S0, S1, S2, S3, T0, T1, T2, T3;

#define MC_ISSUE_A(i, V0, V1)                                                \
  { int ch_ = h * 18 + (i); int kk_ = ch_ >> 2, c0_ = (ch_ & 3) << 6;        \
    int ky_ = kk_ / 3, kx_ = kk_ - 3 * ky_;                                  \
    int ys_ = y + ky_ - 1, xs_ = px + kx_ - 1;                               \
    V0 = make_uint4(0, 0, 0, 0); V1 = V0;                                    \
    if (ys_ >= 0 && ys_ < 64 && xs_ >= 0 && xs_ < 64) {                      \
      const u16* p_ = xTb + (((ys_ << 6) + xs_) << 8) + c0_ + (q << 4);      \
      V0 = *(const uint4*)p_; V1 = *(const uint4*)(p_ + 8);                  \
    } }

#define MC_ISSUE_B(i, R0, R1, R2, R3)                                        \
  { int ch_ = h * 18 + (i); int kk_ = ch_ >> 2, c0_ = (ch_ & 3) << 6;        \
    const u16* pw_ = Wm2 + (kk_ << 8) + c0_ + (kq << 3);                     \
    R0 = *(const uint4*)(pw_ + ml * 2304);                                   \
    R1 = *(const uint4*)(pw_ + (16 + ml) * 2304);                            \
    R2 = *(const uint4*)(pw_ + ml * 2304 + 32);                              \
    R3 = *(const uint4*)(pw_ + (16 + ml) * 2304 + 32); }

#define MC_WRITE(buf, V0, V1)                                                \
  { *(uint4*)&As[h][buf][px][q << 4] = V0;                                   \
    *(uint4*)&As[h][buf][px][(q << 4) + 8] = V1; }

#define MC_MFMA(buf, R0, R1, R2, R3)                                         \
  { bf16x8 a0_ = *(const bf16x8*)&As[h][buf][wl * 16 + ml][kq << 3];         \
    acc0 = __builtin_amdgcn_mfma_f32_16x16x32_bf16(a0_, *(const bf16x8*)&R0, acc0, 0,0,0); \
    acc1 = __builtin_amdgcn_mfma_f32_16x16x32_bf16(a0_, *(const bf16x8*)&R1, acc1, 0,0,0); \
    bf16x8 a1_ = *(const bf16x8*)&As[h][buf][wl * 16 + ml][32 + (kq << 3)];  \
    acc0 = __builtin_amdgcn_mfma_f32_16x16x32_bf16(a1_, *(const bf16x8*)&R2, acc0, 0,0,0); \
    acc1 = __builtin_amdgcn_mfma_f32_16x16x32_bf16(a1_, *(const bf16x8*)&R3, acc1, 0,0,0); }

  MC_ISSUE_A(0, VA0, VA1)
  MC_ISSUE_A(1, VB0, VB1)
  MC_ISSUE_B(0, S0, S1, S2, S3)
#pragma unroll 1
  for (int i2 = 0; i2 < 18; i2 += 2) {
    MC_WRITE(0, VA0, VA1)
    bar();
    if (i2 + 2 < 18) MC_ISSUE_A(i2 + 2, VA0, VA1)
    MC_ISSUE_B(i2 + 1, T0, T1, T2, T3)
    MC_MFMA(0, S0, S1, S2, S3)
    MC_WRITE(1, VB0, VB1)
    bar();
    if (i2 + 3 < 18) MC_ISSUE_A(i2 + 3, VB0, VB1)
    if (i2 + 2 < 18) MC_ISSUE_B(i2 + 2, S0, S1, S2, S3)
    MC_MFMA(1, T0, T1, T2, T3)
  }
#pragma unroll
  for (int r = 0; r < 4; ++r) {
    mods2[h][ml][wl * 16 + kq * 4 + r]      = acc0[r];
    mods2[h][16 + ml][wl * 16 + kq * 4 + r] = acc1[r];
  }
  __syncthreads();
  for (int i2 = t; i2 < 576; i2 += 512) {
    int kk = i2 >> 6, pxx_i = i2 & 63;
    float dy = mods2[0][2 * kk][pxx_i] + mods2[1][2 * kk][pxx_i];
    float dx = mods2[0][2 * kk + 1][pxx_i] + mods2[1][2 * kk + 1][pxx_i];
    float mv = mods2[0][18 + kk][pxx_i] + mods2[1][18 + kk][pxx_i];
    float msk = 1.f / (1.f + __expf(-mv));
    int ky = kk / 3, kx = kk - 3 * ky;
    float py  = dy + (float)(y + ky - 1);
    float pxx = dx + (float)(pxx_i + kx - 1);
    float y0f = floorf(py), x0f = floorf(pxx);
    float fy = py - y0f, fx = pxx - x0f;
    int y0 = (int)y0f, x0 = (int)x0f;
    float vy0 = (y0 >= 0 && y0 < 64) ? msk : 0.f;
    float vy1 = (y0 + 1 >= 0 && y0 + 1 < 64) ? msk : 0.f;
    float w00 = (1.f - fy) * (1.f - fx) * vy0;
    float w01 = (1.f - fy) * fx * vy0;
    float w10 = fy * (1.f - fx) * vy1;
    float w11 = fy * fx * vy1;
    int xb2 = min(max(x0, 0), 62);
    float wA0 = (xb2 == x0) ? w00 : ((xb2 == x0 + 1) ? w01 : 0.f);
    float wB0 = (xb2 + 1 == x0) ? w00 : ((xb2 + 1 == x0 + 1) ? w01 : 0.f);
    float wA1 = (xb2 == x0) ? w10 : ((xb2 == x0 + 1) ? w11 : 0.f);
    float wB1 = (xb2 + 1 == x0) ? w10 : ((xb2 + 1 == x0 + 1) ? w11 : 0.f);
    int ib0 = min(max(y0, 0), 63) * 64 + xb2;
    int ib1 = min(max(y0 + 1, 0), 63) * 64 + xb2;
    int ci = ((b * 9 + kk) << 12) + (y << 6) + pxx_i;
    cidx[ci] = make_int2(ib0, ib1);
    cwt[ci]  = make_float4(wA0, wB0, wA1, wB1);
  }
#undef MC_ISSUE_A
#undef MC_ISSUE_B
#undef MC_WRITE
#undef MC_MFMA
}

// -------- K2: fused gather + GEMM, prefetch-2 gathers + soft barriers --------
// grid 256 swizzled, 512 threads (8 waves). Wave w owns n in [w*32, w*32+32).
__global__ __launch_bounds__(512) void k_main(
    const u16* __restrict__ xT, const u16* __restrict__ W2,
    const float* __restrict__ b_def,
    const int2* __restrict__ cidx, const float4* __restrict__ cwt,
    float* __restrict__ out) {
  __shared__ __align__(16) u16 As[2][64][72];
  __shared__ __align__(16) int2 Cs_i[576];
  __shared__ __align__(16) float4 Cs_w[576];
  int t = threadIdx.x;
  int l = t & 63;
  int w = t >> 6;
  int g = blockIdx.x;
  int b = (g & 7) >> 1, y = ((g >> 3) << 1) + (g & 1);
  const u16* xTb = xT + (b << 20);
  int gm = t >> 3, go = t & 7;          // gather: pixel, channel-octet
  int ml = l & 15, kq = l >> 4;
  int nrow0 = w * 32 + ml, nrow1 = nrow0 + 16;

  f32x4 zero = {0.f, 0.f, 0.f, 0.f};
  f32x4 acc[4][2];
#pragma unroll
  for (int i = 0; i < 4; ++i) { acc[i][0] = zero; acc[i][1] = zero; }

  for (int i = t; i < 576; i += 512) {
    int kk = i >> 6, px = i & 63;
    int ci = ((b * 9 + kk) << 12) + (y << 6) + px;
    Cs_i[i] = cidx[ci];
    Cs_w[i] = cwt[ci];
  }
  bar();

  uint4 A00, A01, A02, A03; float4 wt0;   // gather set 0
  uint4 A10, A11, A12, A13; float4 wt1;   // gather set 1
  uint4 RA0, RA1, RA2, RA3;               // B set 0
  uint4 RB0, RB1, RB2, RB3;               // B set 1

#define ISSUE_A(chunk, a0, a1, a2, a3, wt)                                   \
  { int kk_ = (chunk) >> 2, c0_ = ((chunk) & 3) << 6;                        \
    int cI_ = (kk_ << 6) + gm;                                               \
    int2 ib_ = Cs_i[cI_];                                                    \
    wt = Cs_w[cI_];                                                          \
    const u16* p0_ = xTb + (ib_.x << 8) + c0_ + (go << 3);                   \
    const u16* p1_ = xTb + (ib_.y << 8) + c0_ + (go << 3);                   \
    a0 = *(const uint4*)p0_;  a1 = *(const uint4*)(p0_ + 256);               \
    a2 = *(const uint4*)p1_;  a3 = *(const uint4*)(p1_ + 256); }

#define ISSUE_B(chunk, R0, R1, R2, R3)                                       \
  { int kk_ = (chunk) >> 2, c0_ = ((chunk) & 3) << 6;                        \
    const u16* pw_ = W2 + (kk_ << 8) + c0_ + (kq << 3);                      \
    R0 = *(const uint4*)(pw_ + nrow0 * 2304);                                \
    R1 = *(const uint4*)(pw_ + nrow1 * 2304);                                \
    R2 = *(const uint4*)(pw_ + nrow0 * 2304 + 32);                           \
    R3 = *(const uint4*)(pw_ + nrow1 * 2304 + 32); }

#define UNPACK(CUR, a0, a1, a2, a3, wt)                                      \
  { u32 q0_ = bil2(a0.x, a1.x, a2.x, a3.x, wt);                              \
    u32 q1_ = bil2(a0.y, a1.y, a2.y, a3.y, wt);                              \
    u32 q2_ = bil2(a0.z, a1.z, a2.z, a3.z, wt);                              \
    u32 q3_ = bil2(a0.w, a1.w, a2.w, a3.w, wt);                              \
    *(uint4*)&As[CUR][gm][go << 3] = make_uint4(q0_, q1_, q2_, q3_); }

#define DOMFMA(CUR, R0, R1, R2, R3)                                          \
  { bf16x8 a0_ = *(const bf16x8*)&As[CUR][ml][kq << 3];                      \
    bf16x8 a1_ = *(const bf16x8*)&As[CUR][16 + ml][kq << 3];                 \
    bf16x8 a2_ = *(const bf16x8*)&As[CUR][32 + ml][kq << 3];                 \
    bf16x8 a3_ = *(const bf16x8*)&As[CUR][48 + ml][kq << 3];                 \
    bf16x8 b0_ = *(const bf16x8*)&R0;                                        \
    bf16x8 b1_ = *(const bf16x8*)&R1;                                        \
    acc[0][0] = __builtin_amdgcn_mfma_f32_16x16x32_bf16(a0_, b0_, acc[0][0], 0,0,0); \
    acc[1][0] = __builtin_amdgcn_mfma_f32_16x16x32_bf16(a1_, b0_, acc[1][0], 0,0,0); \
    acc[2][0] = __builtin_amdgcn_mfma_f32_16x16x32_bf16(a2_, b0_, acc[2][0], 0,0,0); \
    acc[3][0] = __builtin_amdgcn_mfma_f32_16x16x32_bf16(a3_, b0_, acc[3][0], 0,0,0); \
    acc[0][1] = __builtin_amdgcn_mfma_f32_16x16x32_bf16(a0_, b1_, acc[0][1], 0,0,0); \
    acc[1][1] = __builtin_amdgcn_mfma_f32_16x16x32_bf16(a1_, b1_, acc[1][1], 0,0,0); \
    acc[2][1] = __builtin_amdgcn_mfma_f32_16x16x32_bf16(a2_, b1_, acc[2][1], 0,0,0); \
    acc[3][1] = __builtin_amdgcn_mfma_f32_16x16x32_bf16(a3_, b1_, acc[3][1], 0,0,0); \
    a0_ = *(const bf16x8*)&As[CUR][ml][32 + (kq << 3)];                      \
    a1_ = *(const bf16x8*)&As[CUR][16 + ml][32 + (kq << 3)];                 \
    a2_ = *(const bf16x8*)&As[CUR][32 + ml][32 + (kq << 3)];                 \
    a3_ = *(const bf16x8*)&As[CUR][48 + ml][32 + (kq << 3)];                 \
    b0_ = *(const bf16x8*)&R2;                                               \
    b1_ = *(const bf16x8*)&R3;                                               \
    acc[0][0] = __builtin_amdgcn_mfma_f32_16x16x32_bf16(a0_, b0_, acc[0][0], 0,0,0); \
    acc[1][0] = __builtin_amdgcn_mfma_f32_16x16x32_bf16(a1_, b0_, acc[1][0], 0,0,0); \
    acc[2][0] = __builtin_amdgcn_mfma_f32_16x16x32_bf16(a2_, b0_, acc[2][0], 0,0,0); \
    acc[3][0] = __builtin_amdgcn_mfma_f32_16x16x32_bf16(a3_, b0_, acc[3][0], 0,0,0); \
    acc[0][1] = __builtin_amdgcn_mfma_f32_16x16x32_bf16(a0_, b1_, acc[0][1], 0,0,0); \
    acc[1][1] = __builtin_amdgcn_mfma_f32_16x16x32_bf16(a1_, b1_, acc[1][1], 0,0,0); \
    acc[2][1] = __builtin_amdgcn_mfma_f32_16x16x32_bf16(a2_, b1_, acc[2][1], 0,0,0); \
    acc[3][1] = __builtin_amdgcn_mfma_f32_16x16x32_bf16(a3_, b1_, acc[3][1], 0,0,0); }

  ISSUE_A(0, A00, A01, A02, A03, wt0)
  ISSUE_A(1, A10, A11, A12, A13, wt1)
  ISSUE_B(0, RA0, RA1, RA2, RA3)
#pragma unroll 1
  for (int c2 = 0; c2 < 36; c2 += 2) {
    UNPACK(0, A00, A01, A02, A03, wt0)
    bar();
    if (c2 + 2 < 36) ISSUE_A(c2 + 2, A00, A01, A02, A03, wt0)
    ISSUE_B(c2 + 1, RB0, RB1, RB2, RB3)
    DOMFMA(0, RA0, RA1, RA2, RA3)
    UNPACK(1, A10, A11, A12, A13, wt1)
    bar();
    if (c2 + 3 < 36) ISSUE_A(c2 + 3, A10, A11, A12, A13, wt1)
    if (c2 + 2 < 36) ISSUE_B(c2 + 2, RA0, RA1, RA2, RA3)
    DOMFMA(1, RB0, RB1, RB2, RB3)
  }

  // epilogue: bias + f32 stores (C/D: col=n, row=kq*4+r)
#pragma unroll
  for (int nt = 0; nt < 2; ++nt) {
    int n = w * 32 + nt * 16 + ml;
    float bias = b_def[n];
    float* op = out + (((b << 8) + n) << 12) + (y << 6);
#pragma unroll
    for (int mt = 0; mt < 4; ++mt) {
      float4 v;
      v.x = acc[mt][nt][0] + bias;
      v.y = acc[mt][nt][1] + bias;
      v.z = acc[mt][nt][2] + bias;
      v.w = acc[mt][nt][3] + bias;
      *(float4*)(op + mt * 16 + kq * 4) = v;
    }
  }
#undef ISSUE_A
#undef ISSUE_B
#undef UNPACK
#undef DOMFMA
}

// -------------------- launcher --------------------
extern "C" void kernel_launch(void* const* d_in, const int* in_sizes, int n_in,
                              void* d_out, int out_size, void* d_ws, size_t ws_size,
                              hipStream_t stream) {
  const float* x     = (const float*)d_in[0];
  const float* w_mod = (const float*)d_in[1];
  const float* w_def = (const float*)d_in[2];
  const float* b_def = (const float*)d_in[3];
  float* out = (float*)d_out;
  char* ws = (char*)d_ws;
  // ws: xT 8,388,608 | W2 1,179,648 | Wm2 147,456 | cidx 1,179,648 | cwt 2,359,296
  u16*    xT   = (u16*)(ws);
  u16*    W2   = (u16*)(ws + 8388608);
  u16*    Wm2  = (u16*)(ws + 8388608 + 1179648);
  int2*   cidx = (int2*)(ws + 8388608 + 1179648 + 147456);
  float4* cwt  = (float4*)(ws + 8388608 + 1179648 + 147456 + 1179648);

  hipLaunchKernelGGL(k_prep, dim3(1312), dim3(256), 0, stream, x, w_mod, w_def, xT, Wm2, W2);
  hipLaunchKernelGGL(k_modconv, dim3(256), dim3(512), 0, stream, xT, Wm2, cidx, cwt);
  hipLaunchKernelGGL(k_main, dim3(256), dim3(512), 0, stream, xT, W2, b_def, cidx, cwt, out);
}